// Round 3
// baseline (136.831 us; speedup 1.0000x reference)
//
#include <hip/hip_runtime.h>
#include <stdint.h>

// Cost volume, D=4: out[b,s,h,w] = mean_c feat1[b,c,h,w] * feat2[b,c,h,w+s-4]
// feat1/feat2: (8, 256, 96, 320) f32; out: (8, 9, 96, 320) f32.
// Latency-bound fix: global_load_lds ring (depth 4, 5 slots) + counted vmcnt.

constexpr int B  = 8;
constexpr int C  = 256;
constexpr int H  = 96;
constexpr int W  = 320;
constexpr int NS = 9;            // 2*D+1 shifts
constexpr int QT = W / 4;        // 80 float4 per row
constexpr int RPB = 4;           // rows per block
constexpr int NTH = RPB * QT;    // 320 threads = 5 waves
constexpr int NC  = 4;           // channel chunks -> 768 blocks = 3/CU
constexpr int CCH = C / NC;      // 64 channels per chunk
constexpr int HW  = H * W;
constexpr int OUT_ELEMS = B * NS * H * W;   // 2,211,840
constexpr int DEPTH = 4;         // stages in flight
constexpr int SLOTS = DEPTH + 1; // ring slots (extra slot removes WAR hazard)
constexpr int TFL = RPB * W;     // 1280 floats = 5120 B per tile per tensor

typedef const __attribute__((address_space(1))) void* gas_ptr;
typedef __attribute__((address_space(3))) void* las_ptr;

__device__ __forceinline__ void gload16(const float* g, float* l) {
    __builtin_amdgcn_global_load_lds((gas_ptr)g, (las_ptr)l, 16, 0, 0);
}

__global__ void zero_out_kernel(float* __restrict__ out, int n) {
    int i = blockIdx.x * blockDim.x + threadIdx.x;
    int stride = gridDim.x * blockDim.x;
    for (; i < n; i += stride) out[i] = 0.0f;
}

__global__ __launch_bounds__(NTH)
void cv_kernel(const float* __restrict__ f1,
               const float* __restrict__ f2,
               float* __restrict__ part) {
    __shared__ float lA[SLOTS][TFL];   // feat1 tiles
    __shared__ float lB[SLOTS][TFL];   // feat2 tiles   (total 51.2 KB)

    const int tid = threadIdx.x;
    const int q   = tid % QT;
    const int r   = tid / QT;

    const int blk    = blockIdx.x;
    const int cchunk = blk % NC;
    const int rowblk = blk / NC;
    const int hb     = rowblk % (H / RPB);
    const int b      = rowblk / (H / RPB);
    const int h0     = hb * RPB;
    const int c0     = cchunk * CCH;

    // Tile for channel c: 4 contiguous rows (b, c0+c, h0..h0+3, 0..W) = 5120 B.
    // Thread t stages bytes [16t, 16t+16) -> LDS lane-linear (global_load_lds
    // writes wave-uniform base + lane*16; our mapping is exactly that).
    const size_t tbase = ((size_t)(b * C + c0) * H + h0) * (size_t)W;
    const float* g1 = f1 + tbase + 4 * tid;
    const float* g2 = f2 + tbase + 4 * tid;

    // Prologue: stage tiles 0..DEPTH-1 (CCH=64 >> DEPTH, always valid).
    const float* p1 = g1;
    const float* p2 = g2;
#pragma unroll
    for (int i = 0; i < DEPTH; ++i) {
        gload16(p1, &lA[i][4 * tid]);
        gload16(p2, &lB[i][4 * tid]);
        p1 += HW; p2 += HW;          // ends at tile DEPTH
    }

    const bool has_lo = (q > 0);
    const bool has_hi = (q < QT - 1);
    const int  qlo = has_lo ? q - 1 : q;   // clamped; zeroed on use
    const int  qhi = has_hi ? q + 1 : q;

    float acc[4][NS];
#pragma unroll
    for (int j = 0; j < 4; ++j)
#pragma unroll
        for (int s = 0; s < NS; ++s) acc[j][s] = 0.0f;

    int rslot = 0;
    int wslot = DEPTH % SLOTS;   // 4

    for (int c = 0; c < CCH; ++c) {
        // All my ds_reads of the previous iteration retired (slot about to be
        // overwritten), my stage-c loads landed (3 newer stages = 6 ops may
        // remain in flight), then all waves rendezvous.
        asm volatile("s_waitcnt lgkmcnt(0)" ::: "memory");
        asm volatile("s_waitcnt vmcnt(6)" ::: "memory");
        __builtin_amdgcn_s_barrier();
        asm volatile("" ::: "memory");

        // Issue stage c+DEPTH into the slot whose reads finished pre-barrier.
        // Past the end: re-issue the last tile (dummy, slot never read again)
        // to keep the vmcnt arithmetic uniform.
        gload16(p1, &lA[wslot][4 * tid]);
        gload16(p2, &lB[wslot][4 * tid]);
        if (c + DEPTH < CCH - 1) { p1 += HW; p2 += HW; }

        const float4* rowA = (const float4*)(&lA[rslot][r * W]);
        const float4* rowB = (const float4*)(&lB[rslot][r * W]);
        float4 a   = rowA[q];
        float4 x0v = rowB[qlo];
        float4 x1v = rowB[q];
        float4 x2v = rowB[qhi];

        // window x[0..11] = feat2 elements 4q-4 .. 4q+7, zero outside the row
        float x[12] = { has_lo ? x0v.x : 0.f, has_lo ? x0v.y : 0.f,
                        has_lo ? x0v.z : 0.f, has_lo ? x0v.w : 0.f,
                        x1v.x, x1v.y, x1v.z, x1v.w,
                        has_hi ? x2v.x : 0.f, has_hi ? x2v.y : 0.f,
                        has_hi ? x2v.z : 0.f, has_hi ? x2v.w : 0.f };
        float av[4] = {a.x, a.y, a.z, a.w};

#pragma unroll
        for (int j = 0; j < 4; ++j)
#pragma unroll
            for (int s = 0; s < NS; ++s)
                acc[j][s] = fmaf(av[j], x[j + s], acc[j][s]);

        rslot = (rslot == SLOTS - 1) ? 0 : rslot + 1;
        wslot = (wslot == SLOTS - 1) ? 0 : wslot + 1;
    }

    // Store partial sums: part[cchunk][b][s][h][w]
    float* basep = part + (size_t)cchunk * OUT_ELEMS;
    const int h = h0 + r;
#pragma unroll
    for (int s = 0; s < NS; ++s) {
        float4 v = make_float4(acc[0][s], acc[1][s], acc[2][s], acc[3][s]);
        *reinterpret_cast<float4*>(
            basep + ((size_t)(b * NS + s) * H + h) * (size_t)W + 4 * q) = v;
    }
}

// Fallback if ws is too small: simple atomic version (correctness only).
__global__ __launch_bounds__(NTH)
void cv_atomic_kernel(const float* __restrict__ f1,
                      const float* __restrict__ f2,
                      float* __restrict__ out) {
    const int tid = threadIdx.x;
    const int q = tid % QT, r = tid / QT;
    const int blk = blockIdx.x;
    const int cchunk = blk % NC;
    const int rowblk = blk / NC;
    const int hb = rowblk % (H / RPB);
    const int b  = rowblk / (H / RPB);
    const int h  = hb * RPB + r;
    const int c0 = cchunk * CCH;

    const size_t off = ((size_t)(b * C + c0) * H + h) * (size_t)W + 4 * q;
    const float* p1 = f1 + off;
    const float* p2 = f2 + off;
    const bool has_lo = (q > 0), has_hi = (q < QT - 1);
    const int lo = has_lo ? -4 : 0, hi = has_hi ? 4 : 0;

    float acc[4][NS];
#pragma unroll
    for (int j = 0; j < 4; ++j)
#pragma unroll
        for (int s = 0; s < NS; ++s) acc[j][s] = 0.0f;

    for (int c = 0; c < CCH; ++c) {
        float4 a  = *reinterpret_cast<const float4*>(p1);
        float4 x0 = *reinterpret_cast<const float4*>(p2 + lo);
        float4 x1 = *reinterpret_cast<const float4*>(p2);
        float4 x2 = *reinterpret_cast<const float4*>(p2 + hi);
        float x[12] = { has_lo ? x0.x : 0.f, has_lo ? x0.y : 0.f,
                        has_lo ? x0.z : 0.f, has_lo ? x0.w : 0.f,
                        x1.x, x1.y, x1.z, x1.w,
                        has_hi ? x2.x : 0.f, has_hi ? x2.y : 0.f,
                        has_hi ? x2.z : 0.f, has_hi ? x2.w : 0.f };
        float av[4] = {a.x, a.y, a.z, a.w};
#pragma unroll
        for (int j = 0; j < 4; ++j)
#pragma unroll
            for (int s = 0; s < NS; ++s)
                acc[j][s] = fmaf(av[j], x[j + s], acc[j][s]);
        p1 += HW; p2 += HW;
    }
    const float scale = 1.0f / (float)C;
#pragma unroll
    for (int s = 0; s < NS; ++s)
#pragma unroll
        for (int j = 0; j < 4; ++j)
            atomicAdd(out + ((size_t)(b * NS + s) * H + h) * (size_t)W + 4 * q + j,
                      acc[j][s] * scale);
}

__global__ void reduce_kernel(const float* __restrict__ part,
                              float* __restrict__ out, int n4) {
    const float scale = 1.0f / (float)C;
    const float4* p = reinterpret_cast<const float4*>(part);
    float4* o = reinterpret_cast<float4*>(out);
    int i = blockIdx.x * blockDim.x + threadIdx.x;
    int stride = gridDim.x * blockDim.x;
    const int n4e = OUT_ELEMS / 4;
    for (; i < n4; i += stride) {
        float4 v0 = p[i];
        float4 v1 = p[i + n4e];
        float4 v2 = p[i + 2 * n4e];
        float4 v3 = p[i + 3 * n4e];
        float4 rr;
        rr.x = (v0.x + v1.x + v2.x + v3.x) * scale;
        rr.y = (v0.y + v1.y + v2.y + v3.y) * scale;
        rr.z = (v0.z + v1.z + v2.z + v3.z) * scale;
        rr.w = (v0.w + v1.w + v2.w + v3.w) * scale;
        o[i] = rr;
    }
}

extern "C" void kernel_launch(void* const* d_in, const int* in_sizes, int n_in,
                              void* d_out, int out_size, void* d_ws, size_t ws_size,
                              hipStream_t stream) {
    const float* f1 = (const float*)d_in[0];
    const float* f2 = (const float*)d_in[1];
    float* out = (float*)d_out;

    dim3 grid(B * (H / RPB) * NC);   // 768 blocks
    dim3 block(NTH);                 // 320 threads

    const size_t need = (size_t)NC * OUT_ELEMS * sizeof(float);  // 35.4 MB
    if (ws_size >= need) {
        float* part = (float*)d_ws;
        hipLaunchKernelGGL(cv_kernel, grid, block, 0, stream, f1, f2, part);
        const int n4 = OUT_ELEMS / 4;   // 552,960
        hipLaunchKernelGGL(reduce_kernel, dim3(2160), dim3(256), 0, stream,
                           part, out, n4);
    } else {
        hipLaunchKernelGGL(zero_out_kernel, dim3(512), dim3(256), 0, stream,
                           out, out_size);
        hipLaunchKernelGGL(cv_atomic_kernel, grid, block, 0, stream, f1, f2, out);
    }
}